// Round 5
// baseline (112.745 us; speedup 1.0000x reference)
//
#include <hip/hip_runtime.h>
#include <math.h>

#define FBINS 2112            // 33 * 64 bins, layout: bin = w'*64 + h
#define CS 72                 // LDS column stride in floats; 72 % 32 == 8

// Packed complex: (re, im) in a VGPR-pair -> v_pk_*_f32 dual-issue fp32.
typedef float cplx __attribute__((ext_vector_type(2)));
#define MK2(a,b) (cplx){(float)(a), (float)(b)}

__device__ __forceinline__ cplx shufxy(cplx a){ return __builtin_shufflevector(a, a, 1, 0); }
template<int S> __device__ __forceinline__ cplx imul(cplx a){   // (i*S) * a
    return (S > 0) ? shufxy(a) * MK2(-1.f, 1.f) : shufxy(a) * MK2(1.f, -1.f);
}
// Table stores W = exp(+2*pi*i*m/64). S=+1: a*W ; S=-1: a*conj(W).
template<int S> __device__ __forceinline__ cplx cmul_tw(cplx a, cplx w){
    cplx ws = shufxy(w);
    return (S > 0) ? a.x*w + a.y*(ws*MK2(-1.f, 1.f))     // a.x*(wx,wy)+a.y*(-wy,wx)
                   : a.x*(w*MK2(1.f, -1.f)) + a.y*ws;    // a.x*(wx,-wy)+a.y*(wy,wx)
}

// Hardcoded 8-point DFT: X[k] = sum_n v[n] * w8^(n*k), w8 = exp(i*S*pi/4).
template<int S>
__device__ __forceinline__ void dft8(cplx v[8]) {
    const float C = 0.70710678118654752440f;
    cplx t0=v[0]+v[4], t4=v[0]-v[4];
    cplx t1=v[1]+v[5], t5=v[1]-v[5];
    cplx t2=v[2]+v[6], t6=v[2]-v[6];
    cplx t3=v[3]+v[7], t7=v[3]-v[7];
    cplx u0=t0+t2, u2=t0-t2;
    cplx u1=t1+t3, u3=t1-t3;
    v[0]=u0+u1; v[4]=u0-u1;
    cplx m3=imul<S>(u3);
    v[2]=u2+m3; v[6]=u2-m3;
    cplx z0=t4;
    cplx z1 = C*(t5 + imul<S>(t5));          // C*( x-y, y+x ) [S>0] etc.
    cplx z2 = imul<S>(t6);
    cplx z3 = C*(imul<S>(t7) - t7);
    cplx w0=z0+z2, w2=z0-z2;
    cplx w1=z1+z3, w3=z1-z3;
    v[1]=w0+w1; v[5]=w0-w1;
    cplx mb=imul<S>(w3);
    v[3]=w2+mb; v[7]=w2-mb;
}

// Cooperative 64-point DFT among 8 same-wave lanes (j = 0..7), inputs in regs
// as v[n1] = z[8*n1 + j]. Stage-1 exchange uses 64-slot scratch at
// [base..base+64) with XOR-swizzled slots slot(a,b) = 8a + (b^a); with
// base stride == 8 (mod 32) both scatter write and gather read are exactly
// 2 lanes/bank (free). On return v[k2] = X[j + 8*k2].
template<int S>
__device__ __forceinline__ void fft64_from_regs(
    cplx v[8], float* __restrict__ re, float* __restrict__ im,
    int base, int j, const cplx wj[7])
{
    dft8<S>(v);                       // A[j][k1]
    #pragma unroll
    for (int k=1;k<8;++k) v[k] = cmul_tw<S>(v[k], wj[k-1]);  // * w64^(S*j*k1)
    #pragma unroll
    for (int k=0;k<8;++k){ int s=base+8*j+(k^j); re[s]=v[k].x; im[s]=v[k].y; }
    #pragma unroll
    for (int n=0;n<8;++n){ int s=base+8*n+(j^n); v[n]=MK2(re[s],im[s]); }
    dft8<S>(v);                       // X[j + 8*k2]
}

// 56-entry twiddle table: TWS[j*7 + k] = exp(+2*pi*i * j*(k+1) / 64).
__device__ __forceinline__ void init_twtable(cplx* TWS, int tid){
    if (tid < 56) {
        int jj = tid / 7, kk = tid - 7*jj + 1;
        float sn, cs;
        sincosf(6.283185307179586f * (float)(jj*kk) / 64.0f, &sn, &cs);
        TWS[tid] = MK2(cs, sn);
    }
}
__device__ __forceinline__ void load_tw(const cplx* TWS, int j, cplx wj[7]){
    #pragma unroll
    for (int k=0;k<7;++k) wj[k] = TWS[j*7+k];
}

// Forward rfft2 of one 64x64 real image per block; also emits sum(img^2)
// partial for the norm. Output: out[img*2112 + w'*64 + h] * scale.
__global__ __launch_bounds__(256) void fwd_fft_kernel(
    const float* __restrict__ in, cplx* __restrict__ out, float scale,
    float* __restrict__ pn)
{
    __shared__ __align__(16) float SRe[32*CS + 64], SIm[32*CS + 64];
    __shared__ cplx TWS[56];
    __shared__ float red[4];
    const int tid = threadIdx.x, G = tid>>3, j = tid&7;

    init_twtable(TWS, tid);

    const float* img = in + (size_t)blockIdx.x * 4096;

    // row pass: pack rows (G, G+32): z[w] = row_G[w] + i*row_{G+32}[w].
    cplx wj[7];
    {
        cplx v[8];
        float ns = 0.f;
        #pragma unroll
        for (int nn=0;nn<8;++nn){ int w=8*nn+j;
            float a = img[64*G + w], c = img[64*(G+32) + w];
            v[nn] = MK2(a, c);
            ns = fmaf(a, a, ns); ns = fmaf(c, c, ns); }
        #pragma unroll
        for (int off = 32; off; off >>= 1) ns += __shfl_xor(ns, off);
        if ((tid & 63) == 0) red[tid >> 6] = ns;
        __syncthreads();              // TWS ready + red ready
        load_tw(TWS, j, wj);
        int base = CS*G;
        fft64_from_regs<-1>(v, SRe, SIm, base, j, wj);
        #pragma unroll
        for (int k=0;k<8;++k){ int s=base+j+8*k; SRe[s]=v[k].x; SIm[s]=v[k].y; }
    }
    __syncthreads();

    // column pass: group 0 handles packed columns (0,32); group G -> column G.
    {
        cplx v[8];
        if (G == 0) {
            #pragma unroll
            for (int nn=0;nn<8;++nn){
                int r=8*nn+j, p=r&31, hi=r>>5;
                float a0 =SRe[CS*p + 0],  b0 =SIm[CS*p + 0];
                float a32=SRe[CS*p + 32], b32=SIm[CS*p + 32];
                v[nn] = hi ? MK2(b0, b32) : MK2(a0, a32);
            }
        } else {
            const int c = G;
            #pragma unroll
            for (int nn=0;nn<8;++nn){
                int r=8*nn+j, p=r&31, hi=r>>5;
                cplx A  = MK2(SRe[CS*p + c],      SIm[CS*p + c]);
                cplx Bm = MK2(SRe[CS*p + 64 - c], SIm[CS*p + 64 - c]);
                if (!hi) v[nn] = 0.5f*(A + Bm*MK2(1.f,-1.f));
                else     v[nn] = 0.5f*(shufxy(A)*MK2(1.f,-1.f) + shufxy(Bm));
            }
        }
        __syncthreads();              // row-pass data fully consumed into regs
        int base = CS*G;
        fft64_from_regs<-1>(v, SRe, SIm, base, j, wj);
        #pragma unroll
        for (int k=0;k<8;++k){ int s=base+j+8*k; SRe[s]=v[k].x; SIm[s]=v[k].y; }
    }
    __syncthreads();

    // unpack packed column 0 -> true columns 0 and 32; store all.
    cplx* o = out + (size_t)blockIdx.x * FBINS;
    for (int i = tid; i < FBINS; i += 256) {
        int wp = i>>6, h = i&63;
        cplx r;
        if (wp == 0) {
            int h2 = (64-h)&63;
            cplx a = MK2(SRe[h],  SIm[h]);
            cplx bb= MK2(SRe[h2], SIm[h2]);
            r = 0.5f*(a + bb*MK2(1.f,-1.f));
        } else if (wp == 32) {
            int h2 = (64-h)&63;
            cplx a = MK2(SRe[h],  SIm[h]);
            cplx bb= MK2(SRe[h2], SIm[h2]);
            r = 0.5f*(shufxy(a)*MK2(1.f,-1.f) + shufxy(bb));
        } else {
            r = MK2(SRe[CS*wp + h], SIm[CS*wp + h]);
        }
        o[i] = r * scale;
    }
    if (tid == 0) pn[blockIdx.x] = red[0] + red[1] + red[2] + red[3];
}

// One block per (b,n) pair, XCD-tiled: XCD x owns n in [64x, 64x+64).
__global__ __launch_bounds__(256) void corr_kernel(
    const cplx* __restrict__ Xf, const cplx* __restrict__ Yf,
    const float* __restrict__ px, const float* __restrict__ py,
    float* __restrict__ out)
{
    __shared__ __align__(16) float SRe[32*CS + 64], SIm[32*CS + 64];
    __shared__ cplx TWS[56];
    __shared__ float red[4];
    const int tid = threadIdx.x, G = tid>>3, j = tid&7;

    const int blk = blockIdx.x;
    const int xcd = blk & 7, idx = blk >> 3;
    const int n = xcd*64 + (idx & 63);
    const int b = idx >> 6;

    init_twtable(TWS, tid);

    // norm factor (broadcast L2 loads, hidden under step A)
    const float x2 = px[3*b] + px[3*b+1] + px[3*b+2];
    const float y2 = py[3*n] + py[3*n+1] + py[3*n+2];
    const float dinv = rsqrtf(x2 * y2);

    // step A: G[h][w'] = sum_c conj(X)*Y; bin pairs via float4 loads,
    // packed conj-MAC (2 pk_fma per complex product).
    const float4* Xb4 = (const float4*)(Xf + (size_t)b * 3 * FBINS);
    const float4* Yn4 = (const float4*)(Yf + (size_t)n * 3 * FBINS);
    #pragma unroll
    for (int t = 0; t < 5; ++t) {
        int i = tid + t*256;              // pair index, 1056 pairs
        if (i < 1056) {
            cplx acc0 = MK2(0.f,0.f), acc1 = MK2(0.f,0.f);
            #pragma unroll
            for (int ch = 0; ch < 3; ++ch) {
                float4 a = Xb4[ch*1056 + i];
                float4 c = Yn4[ch*1056 + i];
                cplx a0 = MK2(a.x,a.y), a1 = MK2(a.z,a.w);
                cplx c0 = MK2(c.x,c.y), c1 = MK2(c.z,c.w);
                // conj(a)*c = a.x*c + a.y*(c.y, -c.x)
                acc0 += a0.x*c0 + a0.y*(shufxy(c0)*MK2(1.f,-1.f));
                acc1 += a1.x*c1 + a1.y*(shufxy(c1)*MK2(1.f,-1.f));
            }
            int bin = 2*i;
            int s = CS*(bin>>6) + (bin&63);
            *(float2*)&SRe[s] = make_float2(acc0.x, acc1.x);
            *(float2*)&SIm[s] = make_float2(acc0.y, acc1.y);
        }
    }
    __syncthreads();                      // step-A data + TWS ready

    cplx wj[7]; load_tw(TWS, j, wj);

    // step B: inverse FFT along h per column; group 0 packs cols 0 & 32.
    {
        cplx v[8];
        int base = CS*G;
        if (G == 0) {
            #pragma unroll
            for (int nn=0;nn<8;++nn){
                int h = 8*nn + j;
                cplx a = MK2(SRe[h],         SIm[h]);
                cplx c = MK2(SRe[CS*32 + h], SIm[CS*32 + h]);
                v[nn] = a + imul<1>(c);                     // a + i*c
            }
        } else {
            #pragma unroll
            for (int nn=0;nn<8;++nn){ int s = base + 8*nn + j;
                v[nn] = MK2(SRe[s], SIm[s]); }
        }
        fft64_from_regs<1>(v, SRe, SIm, base, j, wj);
        #pragma unroll
        for (int k=0;k<8;++k){ int s = base + j + 8*k; SRe[s]=v[k].x; SIm[s]=v[k].y; }
    }
    __syncthreads();
    // column 0 now holds (c0[h], c32[h]) real pair; cols 1..31 complex.

    // step C: inverse FFT along w, rows packed pairwise (r1=G, r2=G+32).
    float m = -3.4e38f;
    {
        const int r1 = G, r2 = G + 32;
        cplx v[8];
        if (j == 0) {
            v[0] = MK2(SRe[r1], SRe[r2]);                   // w=0: c0 pair
        } else {
            cplx a = MK2(SRe[CS*j + r1], SIm[CS*j + r1]);
            cplx c = MK2(SRe[CS*j + r2], SIm[CS*j + r2]);
            v[0] = a + imul<1>(c);
        }
        #pragma unroll
        for (int nn=1; nn<4; ++nn) {                        // w = 8..31
            int w = 8*nn + j;
            cplx a = MK2(SRe[CS*w + r1], SIm[CS*w + r1]);
            cplx c = MK2(SRe[CS*w + r2], SIm[CS*w + r2]);
            v[nn] = a + imul<1>(c);
        }
        if (j == 0) {
            v[4] = MK2(SIm[r1], SIm[r2]);                   // w=32: c32 pair
        } else {
            int w2 = 32 - j;
            cplx a = MK2(SRe[CS*w2 + r1], SIm[CS*w2 + r1]);
            cplx c = MK2(SRe[CS*w2 + r2], SIm[CS*w2 + r2]);
            v[4] = a*MK2(1.f,-1.f) + shufxy(c);             // conj ext
        }
        #pragma unroll
        for (int nn=5; nn<8; ++nn) {                        // w = 40..63
            int w2 = 64 - (8*nn + j);
            cplx a = MK2(SRe[CS*w2 + r1], SIm[CS*w2 + r1]);
            cplx c = MK2(SRe[CS*w2 + r2], SIm[CS*w2 + r2]);
            v[nn] = a*MK2(1.f,-1.f) + shufxy(c);
        }
        __syncthreads();              // all rows consumed; S becomes scratch
        fft64_from_regs<1>(v, SRe, SIm, CS*G, j, wj);
        #pragma unroll
        for (int k=0;k<8;++k) m = fmaxf(m, fmaxf(v[k].x, v[k].y));
    }
    #pragma unroll
    for (int off = 32; off; off >>= 1) m = fmaxf(m, __shfl_xor(m, off));
    if ((tid & 63) == 0) red[tid >> 6] = m;
    __syncthreads();
    if (tid == 0) {
        float mm = fmaxf(fmaxf(red[0], red[1]), fmaxf(red[2], red[3]));
        out[b*512 + n] = mm * dinv;
    }
}

extern "C" void kernel_launch(void* const* d_in, const int* in_sizes, int n_in,
                              void* d_out, int out_size, void* d_ws, size_t ws_size,
                              hipStream_t stream) {
    const float* x = (const float*)d_in[0];   // (32,3,64,64)
    const float* y = (const float*)d_in[1];   // (512,3,64,64)
    float* out = (float*)d_out;               // (32,512)

    cplx* Xf = (cplx*)d_ws;
    cplx* Yf = Xf + 96 * FBINS;
    float* px = (float*)(Yf + 1536 * FBINS);  // 96 per-(image,channel) sumsq
    float* py = px + 96;                      // 1536 per-(image,channel) sumsq

    fwd_fft_kernel<<<96,   256, 0, stream>>>(x, Xf, 1.0f / 4096.0f, px);
    fwd_fft_kernel<<<1536, 256, 0, stream>>>(y, Yf, 1.0f, py);
    corr_kernel<<<16384, 256, 0, stream>>>(Xf, Yf, px, py, out);
}

// Round 7
// 96.303 us; speedup vs baseline: 1.1707x; 1.1707x over previous
//
#include <hip/hip_runtime.h>
#include <math.h>

#define FBINS 2112            // 33 * 64 bins, layout: bin = w'*64 + h
#define CSC 68                // LDS column stride in cplx units; 68 % 16 == 4

// Packed complex: (re, im) in a VGPR-pair -> v_pk_*_f32 dual-issue fp32.
typedef float cplx __attribute__((ext_vector_type(2)));
typedef __fp16 half2v __attribute__((ext_vector_type(2)));
#define MK2(a,b) (cplx){(float)(a), (float)(b)}

__device__ __forceinline__ cplx shufxy(cplx a){ return __builtin_shufflevector(a, a, 1, 0); }
template<int S> __device__ __forceinline__ cplx imul(cplx a){   // (i*S) * a
    return (S > 0) ? shufxy(a) * MK2(-1.f, 1.f) : shufxy(a) * MK2(1.f, -1.f);
}
// Table stores W = exp(+2*pi*i*m/64). S=+1: a*W ; S=-1: a*conj(W).
template<int S> __device__ __forceinline__ cplx cmul_tw(cplx a, cplx w){
    cplx ws = shufxy(w);
    return (S > 0) ? a.x*w + a.y*(ws*MK2(-1.f, 1.f))
                   : a.x*(w*MK2(1.f, -1.f)) + a.y*ws;
}

__device__ __forceinline__ unsigned pack16(float a, float b){
    half2v h = __builtin_amdgcn_cvt_pkrtz(a, b);
    return __builtin_bit_cast(unsigned, h);
}
__device__ __forceinline__ half2v h2(unsigned u){ return __builtin_bit_cast(half2v, u); }
__device__ __forceinline__ float fdot2(half2v a, half2v b, float c){
#if __has_builtin(__builtin_amdgcn_fdot2)
    return __builtin_amdgcn_fdot2(a, b, c, false);
#else
    return c + (float)a.x*(float)b.x + (float)a.y*(float)b.y;
#endif
}

// Hardcoded 8-point DFT: X[k] = sum_n v[n] * w8^(n*k), w8 = exp(i*S*pi/4).
template<int S>
__device__ __forceinline__ void dft8(cplx v[8]) {
    const float C = 0.70710678118654752440f;
    cplx t0=v[0]+v[4], t4=v[0]-v[4];
    cplx t1=v[1]+v[5], t5=v[1]-v[5];
    cplx t2=v[2]+v[6], t6=v[2]-v[6];
    cplx t3=v[3]+v[7], t7=v[3]-v[7];
    cplx u0=t0+t2, u2=t0-t2;
    cplx u1=t1+t3, u3=t1-t3;
    v[0]=u0+u1; v[4]=u0-u1;
    cplx m3=imul<S>(u3);
    v[2]=u2+m3; v[6]=u2-m3;
    cplx z0=t4;
    cplx z1 = C*(t5 + imul<S>(t5));
    cplx z2 = imul<S>(t6);
    cplx z3 = C*(imul<S>(t7) - t7);
    cplx w0=z0+z2, w2=z0-z2;
    cplx w1=z1+z3, w3=z1-z3;
    v[1]=w0+w1; v[5]=w0-w1;
    cplx mb=imul<S>(w3);
    v[3]=w2+mb; v[7]=w2-mb;
}

// Cooperative 64-point DFT among 8 same-wave lanes (j = 0..7), inputs in regs
// as v[n1] = z[8*n1 + j]. Stage-1 exchange in mem[base..base+64) with
// XOR-swizzled slots slot(a,b) = 8a + (b^a). With CSC % 16 == 4, every
// b64 access pattern in this kernel is uniform 4 lanes/bank-pair (the
// wave64-b64 floor) => no excess conflicts. On return v[k2] = X[j + 8*k2].
template<int S>
__device__ __forceinline__ void fft64_from_regs(
    cplx v[8], cplx* __restrict__ mem, int base, int j, const cplx wj[7])
{
    dft8<S>(v);                       // A[j][k1]
    #pragma unroll
    for (int k=1;k<8;++k) v[k] = cmul_tw<S>(v[k], wj[k-1]);  // * w64^(S*j*k1)
    #pragma unroll
    for (int k=0;k<8;++k) mem[base + 8*j + (k^j)] = v[k];
    #pragma unroll
    for (int n=0;n<8;++n) v[n] = mem[base + 8*n + (j^n)];
    dft8<S>(v);                       // X[j + 8*k2]
}

// 56-entry twiddle table: TWS[j*7 + k] = exp(+2*pi*i * j*(k+1) / 64).
__device__ __forceinline__ void init_twtable(cplx* TWS, int tid){
    if (tid < 56) {
        int jj = tid / 7, kk = tid - 7*jj + 1;
        float sn, cs;
        sincosf(6.283185307179586f * (float)(jj*kk) / 64.0f, &sn, &cs);
        TWS[tid] = MK2(cs, sn);
    }
}
__device__ __forceinline__ void load_tw(const cplx* TWS, int j, cplx wj[7]){
    #pragma unroll
    for (int k=0;k<7;++k) wj[k] = TWS[j*7+k];
}

// Forward rfft2 of one 64x64 real plane per block (unnormalized DFT).
// Outputs packed fp16: oA[bin]=(re,im); if dual, oB[bin]=(-im,re).
// Also emits sum(img^2) partial for the norm.
__global__ __launch_bounds__(256) void fwd_fft_kernel(
    const float* __restrict__ in, unsigned* __restrict__ oA,
    unsigned* __restrict__ oB, float* __restrict__ pn, int dual)
{
    __shared__ __align__(16) cplx CL[32*CSC + 64];
    __shared__ cplx TWS[56];
    __shared__ float red[4];
    const int tid = threadIdx.x, G = tid>>3, j = tid&7;

    init_twtable(TWS, tid);

    const float* img = in + (size_t)blockIdx.x * 4096;

    // row pass: pack rows (G, G+32): z[w] = row_G[w] + i*row_{G+32}[w].
    cplx wj[7];
    {
        cplx v[8];
        float ns = 0.f;
        #pragma unroll
        for (int nn=0;nn<8;++nn){ int w=8*nn+j;
            float a = img[64*G + w], c = img[64*(G+32) + w];
            v[nn] = MK2(a, c);
            ns = fmaf(a, a, ns); ns = fmaf(c, c, ns); }
        #pragma unroll
        for (int off = 32; off; off >>= 1) ns += __shfl_xor(ns, off);
        if ((tid & 63) == 0) red[tid >> 6] = ns;
        __syncthreads();              // TWS ready + red ready
        load_tw(TWS, j, wj);
        int base = CSC*G;
        fft64_from_regs<-1>(v, CL, base, j, wj);
        #pragma unroll
        for (int k=0;k<8;++k) CL[base + j + 8*k] = v[k];
    }
    __syncthreads();

    // column pass: group 0 handles packed columns (0,32); group G -> column G.
    {
        cplx v[8];
        if (G == 0) {
            #pragma unroll
            for (int nn=0;nn<8;++nn){
                int r=8*nn+j, p=r&31, hi=r>>5;
                cplx a0  = CL[CSC*p + 0];
                cplx a32 = CL[CSC*p + 32];
                v[nn] = hi ? MK2(a0.y, a32.y) : MK2(a0.x, a32.x);
            }
        } else {
            const int c = G;
            #pragma unroll
            for (int nn=0;nn<8;++nn){
                int r=8*nn+j, p=r&31, hi=r>>5;
                cplx A  = CL[CSC*p + c];
                cplx Bm = CL[CSC*p + 64 - c];
                if (!hi) v[nn] = 0.5f*(A + Bm*MK2(1.f,-1.f));
                else     v[nn] = 0.5f*(shufxy(A)*MK2(1.f,-1.f) + shufxy(Bm));
            }
        }
        __syncthreads();              // row-pass data fully consumed into regs
        int base = CSC*G;
        fft64_from_regs<-1>(v, CL, base, j, wj);
        #pragma unroll
        for (int k=0;k<8;++k) CL[base + j + 8*k] = v[k];
    }
    __syncthreads();

    // unpack packed column 0 -> true columns 0 and 32; store fp16.
    unsigned* a = oA + (size_t)blockIdx.x * FBINS;
    unsigned* bq = dual ? (oB + (size_t)blockIdx.x * FBINS) : nullptr;
    for (int i = tid; i < FBINS; i += 256) {
        int wp = i>>6, h = i&63;
        cplx r;
        if (wp == 0) {
            int h2i = (64-h)&63;
            cplx av = CL[h], bb = CL[h2i];
            r = 0.5f*(av + bb*MK2(1.f,-1.f));
        } else if (wp == 32) {
            int h2i = (64-h)&63;
            cplx av = CL[h], bb = CL[h2i];
            r = 0.5f*(shufxy(av)*MK2(1.f,-1.f) + shufxy(bb));
        } else {
            r = CL[CSC*wp + h];
        }
        a[i] = pack16(r.x, r.y);
        if (dual) bq[i] = pack16(-r.y, r.x);
    }
    if (tid == 0) pn[blockIdx.x] = red[0] + red[1] + red[2] + red[3];
}

// One block per (b,n) pair, XCD-tiled: XCD x owns n in [64x, 64x+64).
__global__ __launch_bounds__(256) void corr_kernel(
    const unsigned* __restrict__ Xa, const unsigned* __restrict__ Xb,
    const unsigned* __restrict__ Yh,
    const float* __restrict__ px, const float* __restrict__ py,
    float* __restrict__ out)
{
    __shared__ __align__(16) cplx CL[32*CSC + 64];
    __shared__ cplx TWS[56];
    __shared__ float red[4];
    const int tid = threadIdx.x, G = tid>>3, j = tid&7;

    const int blk = blockIdx.x;
    const int xcd = blk & 7, idx = blk >> 3;
    const int n = xcd*64 + (idx & 63);
    const int b = idx >> 6;

    init_twtable(TWS, tid);

    // norm factor; 1/4096 IFFT normalization folded in here.
    const float x2 = px[3*b] + px[3*b+1] + px[3*b+2];
    const float y2 = py[3*n] + py[3*n+1] + py[3*n+2];
    const float dinv = rsqrtf(x2 * y2) * (1.0f/4096.0f);

    // step A: G[bin] = sum_c conj(X)*Y via fp16 dot2 (4 bins per uint4).
    const uint4* pXa = (const uint4*)Xa + (size_t)b * 3 * 528;
    const uint4* pXb = (const uint4*)Xb + (size_t)b * 3 * 528;
    const uint4* pY  = (const uint4*)Yh + (size_t)n * 3 * 528;
    #pragma unroll
    for (int t = 0; t < 3; ++t) {
        int i = tid + (t<<8);             // 4-bin group index, 528 groups
        if (i < 528) {
            float r0=0,i0=0,r1=0,i1=0,r2=0,i2=0,r3=0,i3=0;
            #pragma unroll
            for (int ch = 0; ch < 3; ++ch) {
                uint4 ua = pXa[ch*528 + i];
                uint4 ub = pXb[ch*528 + i];
                uint4 uy = pY [ch*528 + i];
                r0 = fdot2(h2(ua.x), h2(uy.x), r0);  i0 = fdot2(h2(ub.x), h2(uy.x), i0);
                r1 = fdot2(h2(ua.y), h2(uy.y), r1);  i1 = fdot2(h2(ub.y), h2(uy.y), i1);
                r2 = fdot2(h2(ua.z), h2(uy.z), r2);  i2 = fdot2(h2(ub.z), h2(uy.z), i2);
                r3 = fdot2(h2(ua.w), h2(uy.w), r3);  i3 = fdot2(h2(ub.w), h2(uy.w), i3);
            }
            int bin = 4*i;
            int s = CSC*(bin>>6) + (bin&63);   // 4 bins share one column
            *(float4*)&CL[s]   = make_float4(r0,i0,r1,i1);
            *(float4*)&CL[s+2] = make_float4(r2,i2,r3,i3);
        }
    }
    __syncthreads();                      // step-A data + TWS ready

    cplx wj[7]; load_tw(TWS, j, wj);

    // step B: inverse FFT along h per column; group 0 packs cols 0 & 32.
    {
        cplx v[8];
        int base = CSC*G;
        if (G == 0) {
            #pragma unroll
            for (int nn=0;nn<8;++nn){
                int h = 8*nn + j;
                cplx a = CL[h];
                cplx c = CL[CSC*32 + h];
                v[nn] = a + imul<1>(c);                     // a + i*c
            }
        } else {
            #pragma unroll
            for (int nn=0;nn<8;++nn) v[nn] = CL[base + 8*nn + j];
        }
        fft64_from_regs<1>(v, CL, base, j, wj);
        #pragma unroll
        for (int k=0;k<8;++k) CL[base + j + 8*k] = v[k];
    }
    __syncthreads();
    // column 0 now holds (c0[h], c32[h]) real pair; cols 1..31 complex.

    // step C: inverse FFT along w, rows packed pairwise (r1=G, r2=G+32).
    float m = -3.4e38f;
    {
        const int r1 = G, r2 = G + 32;
        cplx v[8];
        if (j == 0) {
            cplx a = CL[r1], c = CL[r2];
            v[0] = MK2(a.x, c.x);                           // w=0: c0 pair
            v[4] = MK2(a.y, c.y);                           // w=32: c32 pair
        } else {
            cplx a = CL[CSC*j + r1], c = CL[CSC*j + r2];
            v[0] = a + imul<1>(c);
            int w2 = 32 - j;
            cplx a2 = CL[CSC*w2 + r1], c2 = CL[CSC*w2 + r2];
            v[4] = a2*MK2(1.f,-1.f) + shufxy(c2);           // conj ext
        }
        #pragma unroll
        for (int nn=1; nn<4; ++nn) {                        // w = 8..31
            int w = 8*nn + j;
            cplx a = CL[CSC*w + r1], c = CL[CSC*w + r2];
            v[nn] = a + imul<1>(c);
        }
        #pragma unroll
        for (int nn=5; nn<8; ++nn) {                        // w = 40..63
            int w2 = 64 - (8*nn + j);
            cplx a = CL[CSC*w2 + r1], c = CL[CSC*w2 + r2];
            v[nn] = a*MK2(1.f,-1.f) + shufxy(c);
        }
        __syncthreads();              // all rows consumed; CL becomes scratch
        fft64_from_regs<1>(v, CL, CSC*G, j, wj);
        #pragma unroll
        for (int k=0;k<8;++k) m = fmaxf(m, fmaxf(v[k].x, v[k].y));
    }
    #pragma unroll
    for (int off = 32; off; off >>= 1) m = fmaxf(m, __shfl_xor(m, off));
    if ((tid & 63) == 0) red[tid >> 6] = m;
    __syncthreads();
    if (tid == 0) {
        float mm = fmaxf(fmaxf(red[0], red[1]), fmaxf(red[2], red[3]));
        out[b*512 + n] = mm * dinv;
    }
}

extern "C" void kernel_launch(void* const* d_in, const int* in_sizes, int n_in,
                              void* d_out, int out_size, void* d_ws, size_t ws_size,
                              hipStream_t stream) {
    const float* x = (const float*)d_in[0];   // (32,3,64,64)
    const float* y = (const float*)d_in[1];   // (512,3,64,64)
    float* out = (float*)d_out;               // (32,512)

    // workspace: Xa[96*2112] u32 | Xb[96*2112] u32 | Yh[1536*2112] u32 | px[96] | py[1536]
    unsigned* Xa = (unsigned*)d_ws;
    unsigned* Xb = Xa + 96 * FBINS;
    unsigned* Yh = Xb + 96 * FBINS;
    float* px = (float*)(Yh + 1536 * FBINS);
    float* py = px + 96;

    fwd_fft_kernel<<<96,   256, 0, stream>>>(x, Xa, Xb, px, 1);
    fwd_fft_kernel<<<1536, 256, 0, stream>>>(y, Yh, nullptr, py, 0);
    corr_kernel<<<16384, 256, 0, stream>>>(Xa, Xb, Yh, px, py, out);
}